// Round 8
// baseline (269.901 us; speedup 1.0000x reference)
//
#include <hip/hip_runtime.h>

#define SS 1024
#define BB 128
#define HH 1024
#define DD 2048
#define NROWS (SS*BB)            // 131072 (t,b) rows
#define NSEG 16
#define TSEG 64                  // segment = 64 timesteps
#define ROWSEG (TSEG*BB)         // 8192 rows per segment
#define NSCANB 4                 // blocks 0..3 -> 16 scan waves
#define NK1B   512               // 2048 k1 waves (read x -> pre), seg-ordered
#define NK3B   504               // 2016 k3 waves (s_out -> out broadcast)
#define NBLK   (NSCANB+NK1B+NK3B)  // 1020 blocks <= 4/CU x 256CU -> co-resident
#define K1WAVES 2048
#define L2E  1.4426950408889634f

// flags layout (ints, 128B-strided):
//   k1done shard: flags[(seg*8+shard)*32], target 256 each (8 shards = 2048 waves)
//   scandone:     flags[4096 + seg*32],    target 16
#define K1FLAG(s,sh) (((s)*8 + (sh))*32)
#define SCFLAG(s)    (4096 + (s)*32)
#define FLAG_INTS    4608

typedef float f32x4 __attribute__((ext_vector_type(4)));

__device__ __forceinline__ float fast_rcp(float x)  { return __builtin_amdgcn_rcpf(x); }
__device__ __forceinline__ float exp2_(float x)     { return __builtin_amdgcn_exp2f(x); }

// Write-through stores (sc0 sc1): payload lands at the device coherence
// point, no dirty L2 copy. NOT tracked by the compiler's vmcnt bookkeeping
// -- the scan/k1 loops keep compiler loads away from asm stores so no
// silent ACK-drains (R17 lesson).
__device__ __forceinline__ void st_wt(float* p, float v){
    asm volatile("global_store_dword %0, %1, off sc0 sc1" :: "v"(p), "v"(v));
}
__device__ __forceinline__ void st_wt_x4(float* p, f32x4 v){
    asm volatile("global_store_dwordx4 %0, %1, off sc0 sc1" :: "v"(p), "v"(v));
}

template<int CTRL>
__device__ __forceinline__ float qperm(float x){
    return __int_as_float(__builtin_amdgcn_update_dpp(0, __float_as_int(x), CTRL, 0xF, 0xF, true));
}
__device__ __forceinline__ float rowshr4(float x){
    return __int_as_float(__builtin_amdgcn_update_dpp(0, __float_as_int(x), 0x114, 0xF, 0xF, true));
}

// R19: (a) k1 remapped so each wave computes 4 consecutive timesteps of ONE
// batch -> pre write is a single st_wt_x4 (lanes 0-3) per segment per wave
// (was 16 scattered WT dwords + 4 slow ACKs at every vmcnt(0) boundary).
// (b) wake latency: s_sleep(2)/(1) polls (was 8/32 -> ~0.85us/segment lag).
// Scan and k3 are byte-identical to R18's verified versions otherwise.
__global__ __launch_bounds__(256, 4) void lstm_df(
    const float* __restrict__ x, const float* __restrict__ W,
    const float* __restrict__ bias, float* out,
    float* __restrict__ s_out, float* __restrict__ finals,
    int* __restrict__ flags)
{
    __shared__ int ready;                    // k3 blocks: highest segment+1 ready
    float* pre = out + (size_t)NROWS * HH;   // hT/cT rows (2 MB) as pre scratch
    const int tid  = threadIdx.x;
    const int lane = tid & 63;
    const int wv   = tid >> 6;
    const int blk  = blockIdx.x;

    if (blk < NSCANB) {
        // ---------------- scan wave (16 waves, 8 batches each) ----------------
        const int sw   = blk*4 + wv;          // 0..15
        const int gate = lane & 3;
        const int L    = (lane >> 2) & 1;
        const int lb   = lane >> 3;
        const int bb   = sw*8 + lb;

        // 12 weight sums computed in-register
        float sh = 0.f, sx = 0.f;
        for (int q = 0; q < 12; ++q) {
            const int base = (q < 4) ? q*DD
                           : (q < 8) ? 4*DD + (q-4)*DD
                                     : 4*DD + (q-8)*DD + HH;
            float v = 0.f;
            #pragma unroll
            for (int k = 0; k < 16; ++k) v += W[base + lane + k*64];
            #pragma unroll
            for (int off = 32; off >= 1; off >>= 1) v += __shfl_xor(v, off, 64);
            if (q == L*4 + gate) sh = v;
            if (q == 8 + gate)   sx = v;
        }
        const float sc  = (gate == 1) ? (2.0f*L2E) : (-L2E);
        const float s_h = sh * sc;
        const float sxc = L ? sx * sc : 0.0f;
        const float pcc = L ? bias[4+gate] * sc : 0.0f;
        const float Ac  = (gate == 1) ? 1.0f : 0.0f;
        const float Bc  = (gate == 0) ? (2.0f*L2E) : ((gate == 1) ? -2.0f : 1.0f);

        const float* pcol = pre + ((size_t)bb << 12) + gate*TSEG;  // + s*256 + ts
        float* so = s_out + (size_t)bb * SS;                        // + t

        float h = 0.f, cp = 0.f, h0d1 = 0.f, h0d2 = 0.f;           // persistent
        float hb0 = 0.f, hb1 = 0.f, hb2 = 0.f, hb3 = 0.f;          // h batch (slot=t&3)

        for (int s = 0; s < NSEG; ++s) {
            // wait k1(s): sum of 8 shards == 2048
            {
                int guard = 0;
                for (;;) {
                    int tot = 0;
                    #pragma unroll
                    for (int i = 0; i < 8; ++i)
                        tot += __hip_atomic_load(&flags[K1FLAG(s,i)], __ATOMIC_RELAXED, __HIP_MEMORY_SCOPE_AGENT);
                    if (tot >= K1WAVES) break;
                    __builtin_amdgcn_s_sleep(2);
                    if (++guard > (1<<22)) break;   // never hit legitimately
                }
                asm volatile("" ::: "memory");      // no payload-load hoisting
            }
            const int t_lo = s*TSEG, t_hi = t_lo + TSEG;

            // load the lane's full segment column (64 floats, contiguous)
            const float* pb = pcol + s*256;
            f32x4 sv[16];
            #pragma unroll
            for (int q = 0; q < 16; ++q)
                asm volatile("global_load_dwordx4 %0, %1, off offset:%2"
                             : "=v"(sv[q]) : "v"(pb), "i"(q*16));
            asm volatile("s_waitcnt vmcnt(0)" ::: "memory");
            __builtin_amdgcn_sched_barrier(0);      // rule #18: pin VALU after wait

            #pragma unroll
            for (int u = 0; u < TSEG; ++u) {
                const float p = L ? pcc : sv[u>>2][u&3];

                const float P = fmaf(h0d2, sxc, p);      // L1 consumes h0_{t-2}
                const float g = fmaf(h, s_h, P);
                const float v = fmaf(Bc, fast_rcp(1.0f + exp2_(g)), Ac);
                const float w = v * qperm<0xB1>(v);
                const float cpn = fmaf(qperm<0xAA>(v), cp, qperm<0x00>(w));
                const float th = fmaf(-2.0f, fast_rcp(1.0f + exp2_(cpn)), 1.0f);
                const float hn = qperm<0xFF>(v) * th;
                // first 2 steps of each segment: L1 redoes steps done by the
                // previous segment's flush (or spin-up at t=0) -> discard.
                const bool disc = (u < 2) && L;
                h  = disc ? h  : hn;
                cp = disc ? cp : cpn;
                h0d2 = h0d1;
                h0d1 = rowshr4(h);                       // L0 h -> L1 quad (DPP)

                // L1's h at loop-u is h1 for row tau = t_lo+u-2; slot = tau&3
                if (((u+2)&3)==0) hb0 = h;
                else if (((u+2)&3)==1) hb1 = h;
                else if (((u+2)&3)==2) hb2 = h;
                else hb3 = h;
                // store batch of 4 rows (tau-3..tau) once slot 3 filled;
                // skip u==1 (covers previous segment, already written)
                if ((u&3)==1 && u>=5 && L && gate==0) {
                    f32x4 hv = {hb0,hb1,hb2,hb3};
                    st_wt_x4(so + t_lo + u - 5, hv);
                }
            }

            const float h0f = h, c0f = cp;       // L0 finals (flush skips L0)

            // flush: 2 L1-only steps -> rows [t_hi-2, t_hi); slots 2,3 then store
            #pragma unroll
            for (int fs = 0; fs < 2; ++fs) {
                const float p = L ? pcc : sv[0][0];  // L0 value unused (disc)
                const float P = fmaf(h0d2, sxc, p);
                const float g = fmaf(h, s_h, P);
                const float v = fmaf(Bc, fast_rcp(1.0f + exp2_(g)), Ac);
                const float w = v * qperm<0xB1>(v);
                const float cpn = fmaf(qperm<0xAA>(v), cp, qperm<0x00>(w));
                const float th = fmaf(-2.0f, fast_rcp(1.0f + exp2_(cpn)), 1.0f);
                const float hn = qperm<0xFF>(v) * th;
                if (L) { h = hn; cp = cpn;
                         if (fs == 0) hb2 = hn; else hb3 = hn; }
                h0d2 = h0d1;
            }
            if (L && gate == 0) {
                f32x4 hv = {hb0,hb1,hb2,hb3};
                st_wt_x4(so + t_hi - 4, hv);
            }

            if (s == NSEG-1 && gate == 0) {
                if (L) { st_wt(finals + 128 + bb, h);
                         st_wt(finals + 384 + bb, cp  * (0.5f/L2E)); }
                else   { st_wt(finals + bb,       h0f);
                         st_wt(finals + 256 + bb, c0f * (0.5f/L2E)); }
            }

            asm volatile("s_waitcnt vmcnt(0)" ::: "memory");  // payload at IC
            if (lane == 0)
                __hip_atomic_fetch_add(&flags[SCFLAG(s)], 1, __ATOMIC_RELAXED, __HIP_MEMORY_SCOPE_AGENT);
        }
        return;
    }

    if (blk < NSCANB + NK1B) {
        // ---------------- k1 wave (2048 waves, seg-ordered sweep) ----------------
        // R19 remap: wave i owns batch b = i&127, t-quad tq = i>>7. Its 4 rows
        // are 4 consecutive timesteps of one b -> per gate the 4 outputs are
        // contiguous in pre -> ONE st_wt_x4 (lanes 0..3) per segment.
        const int i  = (blk - NSCANB)*4 + wv;    // 0..2047
        const int b  = i & (BB-1);
        const int tq = i >> 7;                   // 0..15
        float4 wvv[4][4];
        #pragma unroll
        for (int j = 0; j < 4; ++j)
            #pragma unroll
            for (int it = 0; it < 4; ++it)
                wvv[j][it] = *(const float4*)(W + j*DD + HH + it*256 + lane*4);
        const float4 b0 = *(const float4*)(bias);

        for (int s = 0; s < NSEG; ++s) {
            float g0[4], g1[4], g2[4], g3[4];
            #pragma unroll
            for (int j = 0; j < 4; ++j) {
                const int t = s*TSEG + tq*4 + j;
                const float* xr = x + ((size_t)t * BB + b) * HH;
                float a0 = 0.f, a1 = 0.f, a2 = 0.f, a3 = 0.f;
                #pragma unroll
                for (int it = 0; it < 4; ++it) {
                    f32x4 xv = __builtin_nontemporal_load((const f32x4*)xr + it*64 + lane);
                    a0 = fmaf(xv.x, wvv[0][it].x, fmaf(xv.y, wvv[0][it].y, fmaf(xv.z, wvv[0][it].z, fmaf(xv.w, wvv[0][it].w, a0))));
                    a1 = fmaf(xv.x, wvv[1][it].x, fmaf(xv.y, wvv[1][it].y, fmaf(xv.z, wvv[1][it].z, fmaf(xv.w, wvv[1][it].w, a1))));
                    a2 = fmaf(xv.x, wvv[2][it].x, fmaf(xv.y, wvv[2][it].y, fmaf(xv.z, wvv[2][it].z, fmaf(xv.w, wvv[2][it].w, a2))));
                    a3 = fmaf(xv.x, wvv[3][it].x, fmaf(xv.y, wvv[3][it].y, fmaf(xv.z, wvv[3][it].z, fmaf(xv.w, wvv[3][it].w, a3))));
                }
                #pragma unroll
                for (int off = 32; off >= 1; off >>= 1) {
                    a0 += __shfl_xor(a0, off, 64);
                    a1 += __shfl_xor(a1, off, 64);
                    a2 += __shfl_xor(a2, off, 64);
                    a3 += __shfl_xor(a3, off, 64);
                }
                g0[j] = (a0 + b0.x) * (-L2E);
                g1[j] = (a1 + b0.y) * ( 2.0f * L2E);
                g2[j] = (a2 + b0.z) * (-L2E);
                g3[j] = (a3 + b0.w) * (-L2E);
            }
            if (lane < 4) {
                f32x4 pv;
                #pragma unroll
                for (int j = 0; j < 4; ++j)
                    pv[j] = (lane==0) ? g0[j] : (lane==1) ? g1[j] : (lane==2) ? g2[j] : g3[j];
                st_wt_x4(pre + ((size_t)b << 12) + s*256 + lane*TSEG + tq*4, pv);
            }
            asm volatile("s_waitcnt vmcnt(0)" ::: "memory");  // pre at IC
            if (lane == 0)
                __hip_atomic_fetch_add(&flags[K1FLAG(s, i & 7)], 1, __ATOMIC_RELAXED, __HIP_MEMORY_SCOPE_AGENT);
        }
        return;
    }

    // ---------------- k3 wave (2016 waves, chase scan) ----------------
    if (tid == 0) ready = 0;
    __syncthreads();
    const int u = (blk - NSCANB - NK1B)*4 + wv;  // 0..2015
    const int nrep = (u < 32) ? 2 : 1;           // 2016+32 = 2048 groups of 4 t's
    for (int s = 0; s < NSEG; ++s) {
        // hierarchical wait: tid0 polls global flag, publishes to LDS
        if (tid == 0) {
            int guard = 0;
            while (__hip_atomic_load(&flags[SCFLAG(s)], __ATOMIC_RELAXED, __HIP_MEMORY_SCOPE_AGENT) < 16) {
                __builtin_amdgcn_s_sleep(2);
                if (++guard > (1<<23)) break;    // never hit legitimately
            }
            __hip_atomic_store(&ready, s+1, __ATOMIC_RELAXED, __HIP_MEMORY_SCOPE_WORKGROUP);
        }
        {
            int guard = 0;
            while (__hip_atomic_load(&ready, __ATOMIC_RELAXED, __HIP_MEMORY_SCOPE_WORKGROUP) < s+1) {
                __builtin_amdgcn_s_sleep(1);
                if (++guard > (1<<24)) break;    // never hit legitimately
            }
            asm volatile("" ::: "memory");       // no payload-load hoisting
        }
        for (int rep = 0; rep < nrep; ++rep) {
            const int g  = rep ? (2016 + u) : u;     // group: 4 consecutive t, one b
            const int b  = g >> 4;
            const int t0 = s*TSEG + (g & 15)*4;
            f32x4 v4 = __builtin_nontemporal_load((const f32x4*)(s_out + (size_t)b*SS + t0));
            #pragma unroll
            for (int jj = 0; jj < 4; ++jj) {
                const float vb = (jj==0) ? v4.x : (jj==1) ? v4.y : (jj==2) ? v4.z : v4.w;
                const f32x4 vv = {vb, vb, vb, vb};
                f32x4* dst = (f32x4*)(out + ((size_t)(t0+jj)*BB + b) * HH);
                #pragma unroll
                for (int it = 0; it < 4; ++it)
                    __builtin_nontemporal_store(vv, dst + it*64 + lane);
            }
        }
    }
    if (u < 512) {
        // finals rows: safe to overwrite pre region (scan fully done)
        const float v = __builtin_nontemporal_load(finals + u);
        const f32x4 vv = {v, v, v, v};
        f32x4* dst = (f32x4*)(out + (size_t)(NROWS + u) * HH);
        #pragma unroll
        for (int it = 0; it < 4; ++it)
            __builtin_nontemporal_store(vv, dst + it*64 + lane);
    }
}

extern "C" void kernel_launch(void* const* d_in, const int* in_sizes, int n_in,
                              void* d_out, int out_size, void* d_ws, size_t ws_size,
                              hipStream_t stream) {
    const float* x    = (const float*)d_in[0];   // [S,B,H]
    const float* W    = (const float*)d_in[1];   // [L,4,D]
    const float* bias = (const float*)d_in[2];   // [L,4]
    float* out = (float*)d_out;

    float* s_out  = (float*)d_ws;                // [131072]
    float* finals = s_out + NROWS;               // [512]
    int*   flags  = (int*)(finals + 512);        // [4608] ints

    hipMemsetAsync(flags, 0, FLAG_INTS * sizeof(int), stream);
    hipLaunchKernelGGL(lstm_df, dim3(NBLK), dim3(256), 0, stream,
                       x, W, bias, out, s_out, finals, flags);
}

// Round 9
// 233.674 us; speedup vs baseline: 1.1550x; 1.1550x over previous
//
#include <hip/hip_runtime.h>

#define SS 1024
#define BB 128
#define HH 1024
#define LL 2
#define DD 2048
#define NROWS (SS*BB)            // 131072 (t,b) rows
#define TSEG 512                 // R20: D=4 dispatches, fast scan re-hides S512
#define NSEG 2
#define ROWSEG (TSEG*BB)         // 65536 rows per segment
#define RPW 8                    // rows per wave (ROWSEG / 8192)
#define NSCANB 16                // scanner blocks (1 wave, 8 batches each)
#define NWORKB 2048              // worker blocks (4 waves each -> 8192 waves)
#define L2E  1.4426950408889634f

typedef float f32x4 __attribute__((ext_vector_type(4)));

__device__ __forceinline__ float fast_rcp(float x)  { return __builtin_amdgcn_rcpf(x); }
__device__ __forceinline__ float exp2_(float x)     { return __builtin_amdgcn_exp2f(x); }

template<int CTRL>
__device__ __forceinline__ float qperm(float x){
    return __int_as_float(__builtin_amdgcn_update_dpp(0, __float_as_int(x), CTRL, 0xF, 0xF, true));
}
__device__ __forceinline__ float rowshr4(float x){
    return __int_as_float(__builtin_amdgcn_update_dpp(0, __float_as_int(x), 0x114, 0xF, 0xF, true));
}

// R20: phase-dispatch architecture (R14 correctness model: all cross-cohort
// dependencies are between DISPATCHES) + the R18 scan restructure.
// Dataflow rounds (R15-R19) established: R14's scan was ~320cy/step because
// per-step scalar stores polluted vmcnt (every prefetch wait drained store
// ACKs). Fix ported here: chunked loads (64 scalars, ONE wait per chunk) +
// pure-VALU 64-step unrolled body + h batched into one float4 store per 4
// steps (transposed s_out[b][t]). Scan ~110cy/step -> S512 ~23us, hidden
// under the 41us phase BW time -> D=4 dispatches is the overhead minimum:
//   p0: k1(seg0)                    256 MB R
//   p1: k1(seg1) || scan(seg0)      256 MB R, scan hidden
//   p2: k3(seg0) || scan(seg1)      256 MB W, scan hidden
//   p3: k3(seg1) + finals           258 MB W
// Model: 1.03GB/6.2TB/s + 3x8us = ~190us (R13 at D=4 measured 244.7 with
// the slow scan exposed: 41+68+68+42+24 = 243 -- fit confirms).
__global__ __launch_bounds__(256) void fused_phase(
    const float* __restrict__ x, const float* __restrict__ W,
    const float* __restrict__ bias, float* out,
    float* __restrict__ s_out, float* __restrict__ finals,
    float* __restrict__ sums, float* __restrict__ state,
    int s1, int s2, int s3, int fin)
{
    float* pre = out + (size_t)NROWS * HH;   // hT/cT rows (2 MB) as pre scratch;
                                             // overwritten only by phase-3 finals
    const int tid = threadIdx.x;

    if (blockIdx.x < NSCANB) {
        if (tid >= 64) return;
        const int lane = tid;

        if (s2 < 0) {
            // phase 0: compute 12 weight sums once (block 0 only)
            if (blockIdx.x == 0 && s1 == 0) {
                for (int s = 0; s < 12; ++s) {
                    const int base = (s < 4) ? s*DD
                                   : (s < 8) ? 4*DD + (s-4)*DD
                                             : 4*DD + (s-8)*DD + HH;
                    float v = 0.f;
                    #pragma unroll
                    for (int k = 0; k < 16; ++k) v += W[base + lane + k*64];
                    #pragma unroll
                    for (int off = 32; off >= 1; off >>= 1) v += __shfl_xor(v, off, 64);
                    if (lane == 0) sums[s] = v;
                }
            }
            return;
        }

        // ---------------- scan segment s2 ----------------
        const int gate = lane & 3;
        const int L    = (lane >> 2) & 1;
        const int lb   = lane >> 3;
        const int bb   = blockIdx.x * 8 + lb;

        const float sh = sums[L*4 + gate];       // sum W[L][g][0:H]
        const float sx = sums[8 + gate];         // sum W[1][g][H:2H]
        const float sc  = (gate == 1) ? (2.0f*L2E) : (-L2E);
        const float s_h = sh * sc;
        const float sxc = L ? sx * sc : 0.0f;
        const float pcc = L ? bias[4+gate] * sc : 0.0f;
        const float Ac  = (gate == 1) ? 1.0f : 0.0f;
        const float Bc  = (gate == 0) ? (2.0f*L2E) : ((gate == 1) ? -2.0f : 1.0f);

        const float* pbase = pre + ((size_t)bb << 12) + gate;   // + t*4
        float* so = s_out + (size_t)bb * SS;                    // + t  (transposed)

        const int t_lo = s2 * TSEG, t_hi = t_lo + TSEG;

        float h, cp, h0d1, h0d2;                 // cp = 2*L2E*c
        float4* st = (float4*)state + blockIdx.x*64 + lane;
        if (t_lo == 0) { h = 0.f; cp = 0.f; h0d1 = 0.f; h0d2 = 0.f; }
        else { float4 s = *st; h = s.x; cp = s.y; h0d1 = s.z; h0d2 = s.w; }

        float hb0 = 0.f, hb1 = 0.f, hb2 = 0.f, hb3 = 0.f;  // h batch (slot = t&3)

        float buf[64];
        for (int ch = 0; ch < TSEG/64; ++ch) {
            const int tc = t_lo + ch*64;
            // chunk load: 64 scalars, one compiler wait before first use
            #pragma unroll
            for (int uu = 0; uu < 64; ++uu)
                buf[uu] = pbase[(size_t)(tc + uu) * 4];
            // 64 pure-VALU steps
            #pragma unroll
            for (int uu = 0; uu < 64; ++uu) {
                const float p = L ? pcc : buf[uu];
                const float P = fmaf(h0d2, sxc, p);      // L1 consumes h0_{t-2}
                const float g = fmaf(h, s_h, P);
                const float v = fmaf(Bc, fast_rcp(1.0f + exp2_(g)), Ac);
                const float w = v * qperm<0xB1>(v);
                const float cpn = fmaf(qperm<0xAA>(v), cp, qperm<0x00>(w));
                const float th = fmaf(-2.0f, fast_rcp(1.0f + exp2_(cpn)), 1.0f);
                const float hn = qperm<0xFF>(v) * th;
                // first 2 steps of segment: L1 redoes steps done by previous
                // segment's flush (or spin-up at t=0) -> discard.
                const bool disc = (ch == 0) && (uu < 2) && L;
                h  = disc ? h  : hn;
                cp = disc ? cp : cpn;
                h0d2 = h0d1;
                h0d1 = rowshr4(h);                       // L0 h -> L1 quad (DPP)

                // L1's h at global-u is h1[t_lo+u-2]; slot = (uu+2)&3
                if (((uu+2)&3)==0) hb0 = h;
                else if (((uu+2)&3)==1) hb1 = h;
                else if (((uu+2)&3)==2) hb2 = h;
                else hb3 = h;
                // store 4 rows once slot 3 filled (u%4==1, skip warm-up)
                if (((uu&3)==1) && (ch > 0 || uu >= 5) && L && gate == 0) {
                    *(float4*)(so + tc + uu - 5) = make_float4(hb0,hb1,hb2,hb3);
                }
            }
        }

        const float h0f = h, c0f = cp;           // L0 finals (flush skips L0)

        // flush: 2 L1-only steps -> rows [t_hi-2, t_hi) into slots 2,3
        #pragma unroll
        for (int fs = 0; fs < 2; ++fs) {
            const float p = L ? pcc : buf[63];   // L0 value unused this phase
            const float P = fmaf(h0d2, sxc, p);
            const float g = fmaf(h, s_h, P);
            const float v = fmaf(Bc, fast_rcp(1.0f + exp2_(g)), Ac);
            const float w = v * qperm<0xB1>(v);
            const float cpn = fmaf(qperm<0xAA>(v), cp, qperm<0x00>(w));
            const float th = fmaf(-2.0f, fast_rcp(1.0f + exp2_(cpn)), 1.0f);
            const float hn = qperm<0xFF>(v) * th;
            if (L) { h = hn; cp = cpn;
                     if (fs == 0) hb2 = hn; else hb3 = hn; }
            h0d2 = h0d1;
        }
        if (L && gate == 0)
            *(float4*)(so + t_hi - 4) = make_float4(hb0,hb1,hb2,hb3);

        *st = make_float4(h, cp, h0d1, h0d2);    // state for next segment

        if (t_hi == SS && gate == 0) {
            if (L) { finals[128+bb] = h;   finals[384+bb] = cp  * (0.5f/L2E); }
            else   { finals[bb]     = h0f; finals[256+bb] = c0f * (0.5f/L2E); }
        }
        return;
    }

    // ---------------- BW worker ----------------
    const int lane = tid & 63;
    const int gw   = (blockIdx.x - NSCANB)*4 + (tid >> 6);   // 0..8191

    if (s1 >= 0) {
        // k1: RPW consecutive rows per wave of segment s1 -> transposed pre.
        // x is read exactly once -> nontemporal (skip L2 allocate).
        float4 wv[4][4];
        #pragma unroll
        for (int j = 0; j < 4; ++j)
            #pragma unroll
            for (int it = 0; it < 4; ++it)
                wv[j][it] = *(const float4*)(W + j*DD + HH + it*256 + lane*4);
        const float4 b0 = *(const float4*)(bias);

        #pragma unroll 2
        for (int j = 0; j < RPW; ++j) {
            const int row = s1*ROWSEG + gw*RPW + j;
            const float* xr = x + (size_t)row * HH;
            float a0 = 0.f, a1 = 0.f, a2 = 0.f, a3 = 0.f;
            #pragma unroll
            for (int it = 0; it < 4; ++it) {
                f32x4 xv = __builtin_nontemporal_load((const f32x4*)xr + it*64 + lane);
                a0 = fmaf(xv.x, wv[0][it].x, fmaf(xv.y, wv[0][it].y, fmaf(xv.z, wv[0][it].z, fmaf(xv.w, wv[0][it].w, a0))));
                a1 = fmaf(xv.x, wv[1][it].x, fmaf(xv.y, wv[1][it].y, fmaf(xv.z, wv[1][it].z, fmaf(xv.w, wv[1][it].w, a1))));
                a2 = fmaf(xv.x, wv[2][it].x, fmaf(xv.y, wv[2][it].y, fmaf(xv.z, wv[2][it].z, fmaf(xv.w, wv[2][it].w, a2))));
                a3 = fmaf(xv.x, wv[3][it].x, fmaf(xv.y, wv[3][it].y, fmaf(xv.z, wv[3][it].z, fmaf(xv.w, wv[3][it].w, a3))));
            }
            #pragma unroll
            for (int off = 32; off >= 1; off >>= 1) {
                a0 += __shfl_xor(a0, off, 64);
                a1 += __shfl_xor(a1, off, 64);
                a2 += __shfl_xor(a2, off, 64);
                a3 += __shfl_xor(a3, off, 64);
            }
            if (lane == 0) {
                float4 r = make_float4((a0 + b0.x) * (-L2E),
                                       (a1 + b0.y) * ( 2.0f * L2E),
                                       (a2 + b0.z) * (-L2E),
                                       (a3 + b0.w) * (-L2E));
                const int b = row & (BB-1), t = row >> 7;
                *(float4*)(pre + (((size_t)b << 10) + t) * 4) = r;
            }
        }
    }

    if (s3 >= 0) {
        // k3: 2 groups per wave; group = 4 consecutive t of one b (matches
        // transposed s_out[b][t] -> one broadcast float4 load per group).
        #pragma unroll
        for (int rep = 0; rep < 2; ++rep) {
            const int g  = gw*2 + rep;           // 0..16383
            const int b  = g >> 7;               // 0..127
            const int t0 = s3*TSEG + (g & 127)*4;
            float4 v4 = *(const float4*)(s_out + (size_t)b*SS + t0);
            #pragma unroll
            for (int jj = 0; jj < 4; ++jj) {
                const float vb = (jj==0) ? v4.x : (jj==1) ? v4.y : (jj==2) ? v4.z : v4.w;
                const f32x4 vv = {vb, vb, vb, vb};
                f32x4* dst = (f32x4*)(out + ((size_t)(t0+jj)*BB + b) * HH);
                #pragma unroll
                for (int it = 0; it < 4; ++it)
                    __builtin_nontemporal_store(vv, dst + it*64 + lane);
            }
        }
    }

    if (fin && gw < 512) {
        // finals: hT/cT rows (overwrites the pre region; scan is done)
        const float v = finals[gw];
        const f32x4 vv = {v, v, v, v};
        f32x4* dst = (f32x4*)(out + (size_t)(NROWS + gw) * HH);
        #pragma unroll
        for (int it = 0; it < 4; ++it)
            __builtin_nontemporal_store(vv, dst + it*64 + lane);
    }
}

extern "C" void kernel_launch(void* const* d_in, const int* in_sizes, int n_in,
                              void* d_out, int out_size, void* d_ws, size_t ws_size,
                              hipStream_t stream) {
    const float* x    = (const float*)d_in[0];   // [S,B,H]
    const float* W    = (const float*)d_in[1];   // [L,4,D]
    const float* bias = (const float*)d_in[2];   // [L,4]
    float* out = (float*)d_out;

    float* s_out  = (float*)d_ws;                // [131072] (transposed [b][t])
    float* finals = s_out + NROWS;               // [512]
    float* sums   = finals + 512;                // [16]
    float* state  = sums + 16;                   // [16*64*4] floats (16B aligned)

    // 4-phase pipeline: p0 k1(0); p1 k1(1)||scan(0); p2 k3(0)||scan(1);
    // p3 k3(1)+finals
    for (int p = 0; p < 4; ++p) {
        const int a1 = (p <= 1) ? p : -1;
        const int a2 = (p >= 1 && p <= 2) ? p - 1 : -1;
        const int a3 = (p >= 2) ? p - 2 : -1;
        const int fn = (p == 3) ? 1 : 0;
        hipLaunchKernelGGL(fused_phase, dim3(NSCANB + NWORKB), dim3(256), 0, stream,
                           x, W, bias, out, s_out, finals, sums, state,
                           a1, a2, a3, fn);
    }
}